// Round 9
// baseline (856.267 us; speedup 1.0000x reference)
//
#include <hip/hip_runtime.h>

#define B_ 256
#define D_ 128
#define T_ 1024
#define H_ 64
#define G_ 192
#define TILE_T 64
#define NTILES (T_ / TILE_T)   // 16
#define XGS 65                 // ring t-stride: 65%32=1 -> 2-way max (free)
#define KC 32                  // producer k-chunk
#define WS 194                 // w_s g-stride

typedef float f32x4 __attribute__((ext_vector_type(4)));
typedef unsigned long long u64;

// Fused GRU, 1 launch. Block = 1 batch row, 6 waves, 1 block/CU.
//   waves 0,1,2 : scan, one gate-DOT each; pointwise replicated; ONE
//                 all-to-all b64 hop per step (~253 cyc, measured r7->r8).
//   waves 3,4,5 : register-tiled GEMM producers -> LDS ring.
// Round-9: DS-pipe decongestion. Round-8 producers demanded ~183% of the
// CU's LDS pipe (2xb128 lat re-reads, 8x redundancy), queueing the scan's
// broadcast/hop DS ops (~860 cyc observed vs ~340 issue model). Now:
// 3 producer waves, thread tile 4t x 16g -> 1xb128 lat + 8x broadcast
// float2 w per kk => ~75% DS demand.
__global__ __launch_bounds__(384) void gru_fused(
    const float* __restrict__ lat, const float* __restrict__ hidden_init,
    const float* __restrict__ W_ih, const float* __restrict__ W_hh,
    const float* __restrict__ b_ih, const float* __restrict__ b_hh,
    const float* __restrict__ head_w, const float* __restrict__ head_b,
    float* __restrict__ out)
{
    __shared__ float xg_s[2][G_ * XGS];     // 99,840 B ring [slot][g*XGS+t]
    __shared__ float lat_s[D_ * TILE_T];    // 32,768 B [d][t]
    __shared__ float w_s[KC * WS];          // 24,832 B [kk][g]
    __shared__ float h_priv[3][H_];         // per-scan-wave private h copy
    __shared__ u64  slot[3][2][H_];         // [gate][parity][lane] {tag|val}
    __shared__ unsigned prod_done[2], cons_done[2], pbar;

    const int b    = blockIdx.x;
    const int tid  = threadIdx.x;
    const int lane = tid & 63;
    const int wid  = tid >> 6;

    if (tid < 2) { prod_done[tid] = 0u; cons_done[tid] = 0u; }
    if (tid == 2) pbar = 0u;
    if (tid < 192) { slot[tid >> 6][0][tid & 63] = 0ull;
                     slot[tid >> 6][1][tid & 63] = 0ull; }
    __syncthreads();   // only workgroup barrier (all 6 waves present)

    if (wid < 3) {
        // =============== scan: one gate-dot per wave, 1 hop/step ===============
        __builtin_amdgcn_s_setprio(1);
        const int j   = lane;
        const int row = wid * H_ + j;        // rows: r 0..63 | z 64..127 | n 128..191
        f32x4 w4[16];
        {
            const f32x4* W = (const f32x4*)(W_hh + (size_t)row * H_);
#pragma unroll
            for (int q = 0; q < 16; ++q) w4[q] = W[q];
        }
        asm volatile("" : "+v"(w4[0]), "+v"(w4[1]), "+v"(w4[2]), "+v"(w4[3]),
                          "+v"(w4[4]), "+v"(w4[5]), "+v"(w4[6]), "+v"(w4[7]),
                          "+v"(w4[8]), "+v"(w4[9]), "+v"(w4[10]), "+v"(w4[11]),
                          "+v"(w4[12]), "+v"(w4[13]), "+v"(w4[14]), "+v"(w4[15]));
        const float bias = b_hh[row];
        const float hw   = (wid == 0) ? head_w[j] : 0.f;
        const int o1 = (wid == 0) ? 1 : 0;
        const int o2 = (wid == 2) ? 1 : 2;
        float h = hidden_init[b * H_ + j];
        unsigned sg = 0;

        for (int k = 0; k < NTILES; ++k) {
            const int s = k & 1;
            const unsigned tgt = 3u * (unsigned)((k >> 1) + 1);   // 3 producers
            while (__hip_atomic_load(&prod_done[s], __ATOMIC_ACQUIRE,
                                     __HIP_MEMORY_SCOPE_WORKGROUP) < tgt)
                __builtin_amdgcn_s_sleep(1);
            const float* xr_p = &xg_s[s][(size_t)j * XGS];
            const float* xz_p = &xg_s[s][(size_t)(H_ + j) * XGS];
            const float* xn_p = &xg_s[s][(size_t)(2 * H_ + j) * XGS];

#pragma unroll 2
            for (int t = 0; t < TILE_T; ++t, ++sg) {
                const int par = (int)(sg & 1u);
                // publish h to my private copy (within-wave DS order)
                h_priv[wid][j] = h;
                // x reads hide under the dot (consumed after the hop)
                float xr = xr_p[t], xz = xz_p[t], xn = xn_p[t];
                const f32x4* h4 = (const f32x4*)h_priv[wid];
                float a0 = 0.f, a1 = 0.f, a2 = 0.f, a3 = 0.f;
#pragma unroll
                for (int q = 0; q < 16; ++q) {
                    f32x4 hv = h4[q];           // broadcast read
                    a0 = fmaf(w4[q].x, hv.x, a0); a1 = fmaf(w4[q].y, hv.y, a1);
                    a2 = fmaf(w4[q].z, hv.z, a2); a3 = fmaf(w4[q].w, hv.w, a3);
                }
                float a = ((a0 + a1) + (a2 + a3)) + bias;
                const unsigned want = sg + 1;

                // publish my dot, then poll the other two (single hop)
                u64 pk = ((u64)want << 32) | (u64)__builtin_bit_cast(unsigned, a);
                __hip_atomic_store(&slot[wid][par][j], pk, __ATOMIC_RELAXED,
                                   __HIP_MEMORY_SCOPE_WORKGROUP);
                u64 v1, v2;
                do {
                    v1 = __hip_atomic_load(&slot[o1][par][j], __ATOMIC_RELAXED,
                                           __HIP_MEMORY_SCOPE_WORKGROUP);
                    v2 = __hip_atomic_load(&slot[o2][par][j], __ATOMIC_RELAXED,
                                           __HIP_MEMORY_SCOPE_WORKGROUP);
                } while ((unsigned)(v1 >> 32) != want || (unsigned)(v2 >> 32) != want);
                float b1 = __builtin_bit_cast(float, (unsigned)v1);
                float b2 = __builtin_bit_cast(float, (unsigned)v2);

                float ar, az, an;
                if (wid == 0)      { ar = a;  az = b1; an = b2; }
                else if (wid == 1) { ar = b1; az = a;  an = b2; }
                else               { ar = b1; az = b2; an = a;  }

                // replicated pointwise (identical FP ops in all 3 waves)
                float r   = __builtin_amdgcn_rcpf(1.f + __expf(-(xr + ar)));
                float z   = __builtin_amdgcn_rcpf(1.f + __expf(-(xz + az)));
                float pre = xn + r * an;
                float n   = fmaf(-2.f, __builtin_amdgcn_rcpf(__expf(2.f * pre) + 1.f), 1.f);
                h = fmaf(z, h - n, n);           // (1-z)n + zh
            }
            if (lane == 0)   // each scan wave releases the tile (producers wait 3)
                __hip_atomic_fetch_add(&cons_done[s], 1u, __ATOMIC_RELEASE,
                                       __HIP_MEMORY_SCOPE_WORKGROUP);
        }

        if (wid == 0) {   // all waves hold identical final h
            out[B_ + b * H_ + j] = h;
            float v = h * hw;
#pragma unroll
            for (int off = 32; off > 0; off >>= 1) v += __shfl_down(v, off);
            if (lane == 0) out[b] = v + head_b[0];
        }
    } else {
        // ================= producers: register-tiled GEMM (3 waves) =============
        const int p  = tid - 192;        // 0..191
        const int tx = p & 15;           // 16 t-groups x 4t : t = tx*4 + jj
        const int gy = p >> 4;           // 12 g-groups x 16g: g = gy*16 + i
        const float* latb = lat + (size_t)b * (D_ * T_);
        unsigned phase = 0;

        auto psync = [&]() {
            if ((p & 63) == 0)
                __hip_atomic_fetch_add(&pbar, 1u, __ATOMIC_RELEASE,
                                       __HIP_MEMORY_SCOPE_WORKGROUP);
            ++phase;
            while (__hip_atomic_load(&pbar, __ATOMIC_ACQUIRE,
                                     __HIP_MEMORY_SCOPE_WORKGROUP) < 3u * phase) {}
        };

        float bias[16];
#pragma unroll
        for (int i = 0; i < 16; ++i) bias[i] = b_ih[gy * 16 + i];

        for (int k = 0; k < NTILES; ++k) {
            const int s = k & 1, m = k >> 1;
            if (m >= 1) {
                while (__hip_atomic_load(&cons_done[s], __ATOMIC_ACQUIRE,
                                         __HIP_MEMORY_SCOPE_WORKGROUP) < 3u * (unsigned)m)
                    __builtin_amdgcn_s_sleep(1);
            }
            psync();   // all producers past previous tile's lat_s/w_s

            // stage lat tile [d][t] (coalesced); 8192 floats over 192 threads
#pragma unroll
            for (int i = 0; i < 43; ++i) {
                int f = p + 192 * i;           // f = d*64 + t
                if (f < D_ * TILE_T) {
                    int d = f >> 6, t = f & 63;
                    lat_s[f] = latb[(size_t)d * T_ + k * TILE_T + t];
                }
            }

            float acc[4][16];
#pragma unroll
            for (int jj = 0; jj < 4; ++jj)
#pragma unroll
                for (int i = 0; i < 16; ++i) acc[jj][i] = 0.f;

            for (int kc = 0; kc < D_; kc += KC) {
                psync();   // lat_s staged / previous w_s consumed
#pragma unroll
                for (int i = 0; i < (G_ * KC) / 192; ++i) {   // 32/thread
                    int f = p + 192 * i;
                    int g = f >> 5, kk = f & 31;
                    w_s[kk * WS + g] = W_ih[(size_t)g * D_ + kc + kk];
                }
                psync();   // w_s ready
#pragma unroll 4
                for (int kk = 0; kk < KC; ++kk) {
                    f32x4 l0 = *(const f32x4*)&lat_s[(kc + kk) * 64 + tx * 4];
                    float lv[4] = {l0.x, l0.y, l0.z, l0.w};
                    float wv[16];
#pragma unroll
                    for (int i = 0; i < 8; ++i) {
                        float2 w01 = *(const float2*)&w_s[kk * WS + gy * 16 + 2 * i];
                        wv[2 * i] = w01.x; wv[2 * i + 1] = w01.y;   // 16-lane bcast
                    }
#pragma unroll
                    for (int jj = 0; jj < 4; ++jj)
#pragma unroll
                        for (int i = 0; i < 16; ++i)
                            acc[jj][i] = fmaf(lv[jj], wv[i], acc[jj][i]);
                }
            }

            // write tile to ring slot
            float* xs = xg_s[s];
#pragma unroll
            for (int i = 0; i < 16; ++i)
#pragma unroll
                for (int jj = 0; jj < 4; ++jj)
                    xs[(size_t)(gy * 16 + i) * XGS + tx * 4 + jj] = acc[jj][i] + bias[i];

            if ((p & 63) == 0)
                __hip_atomic_fetch_add(&prod_done[s], 1u, __ATOMIC_RELEASE,
                                       __HIP_MEMORY_SCOPE_WORKGROUP);
        }
    }
}

extern "C" void kernel_launch(void* const* d_in, const int* in_sizes, int n_in,
                              void* d_out, int out_size, void* d_ws, size_t ws_size,
                              hipStream_t stream)
{
    const float* lat   = (const float*)d_in[0];
    const float* hid0  = (const float*)d_in[1];
    const float* W_ih  = (const float*)d_in[2];
    const float* W_hh  = (const float*)d_in[3];
    const float* b_ih  = (const float*)d_in[4];
    const float* b_hh  = (const float*)d_in[5];
    const float* headw = (const float*)d_in[6];
    const float* headb = (const float*)d_in[7];
    float* out = (float*)d_out;

    gru_fused<<<dim3(B_), dim3(384), 0, stream>>>(
        lat, hid0, W_ih, W_hh, b_ih, b_hh, headw, headb, out);
}

// Round 10
// 462.357 us; speedup vs baseline: 1.8520x; 1.8520x over previous
//
#include <hip/hip_runtime.h>

#define B_ 256
#define D_ 128
#define T_ 1024
#define H_ 64
#define G_ 192
#define TILE_T 64
#define NTILES (T_ / TILE_T)   // 16
#define XGS 65                 // ring t-stride: 65%32=1 -> 2-way max (free)
#define KC 32                  // producer k-chunk
#define WS 194                 // w_s g-stride

typedef float f32x4 __attribute__((ext_vector_type(4)));
typedef unsigned long long u64;

// Fused GRU, 1 launch. Block = 1 batch row, 7 waves, 1 block/CU.
//   waves 0,1,2 : scan, one gate-DOT each; pointwise replicated; ONE
//                 all-to-all b64 hop per step (~253 cyc, measured r7->r8).
//                 Round-10: h-broadcast via v_readlane -> SGPR (VALU pipe),
//                 NOT LDS. r8's 16x ds_read_b128 x3 waves serialized ~550
//                 cyc/step in the CU's single DS pipe; scan DS ops/step
//                 drop 23 -> ~6. (r9's producer re-tile spilled: WRITE_SIZE
//                 72KB -> 12.7MB; reverted to r8's proven 8t x 6g tile.)
//   waves 3..6  : register-tiled GEMM producers -> LDS ring (r8 verbatim).
__global__ __launch_bounds__(448, 2) void gru_fused(
    const float* __restrict__ lat, const float* __restrict__ hidden_init,
    const float* __restrict__ W_ih, const float* __restrict__ W_hh,
    const float* __restrict__ b_ih, const float* __restrict__ b_hh,
    const float* __restrict__ head_w, const float* __restrict__ head_b,
    float* __restrict__ out)
{
    __shared__ float xg_s[2][G_ * XGS];     // 99,840 B ring [slot][g*XGS+t]
    __shared__ float lat_s[D_ * TILE_T];    // 32,768 B [d][t]
    __shared__ float w_s[KC * WS];          // 24,832 B [kk][g]
    __shared__ u64  slot[3][2][H_];         // [gate][parity][lane] {tag|val}
    __shared__ unsigned prod_done[2], cons_done[2], pbar;

    const int b    = blockIdx.x;
    const int tid  = threadIdx.x;
    const int lane = tid & 63;
    const int wid  = tid >> 6;

    if (tid < 2) { prod_done[tid] = 0u; cons_done[tid] = 0u; }
    if (tid == 2) pbar = 0u;
    if (tid < 192) { slot[tid >> 6][0][tid & 63] = 0ull;
                     slot[tid >> 6][1][tid & 63] = 0ull; }
    __syncthreads();   // only workgroup barrier (all 7 waves present)

    if (wid < 3) {
        // ========= scan: one gate-dot per wave, readlane h-bcast, 1 hop =========
        __builtin_amdgcn_s_setprio(1);
        const int j   = lane;
        const int row = wid * H_ + j;        // rows: r 0..63 | z 64..127 | n 128..191
        f32x4 w4[16];
        {
            const f32x4* W = (const f32x4*)(W_hh + (size_t)row * H_);
#pragma unroll
            for (int q = 0; q < 16; ++q) w4[q] = W[q];
        }
        asm volatile("" : "+v"(w4[0]), "+v"(w4[1]), "+v"(w4[2]), "+v"(w4[3]),
                          "+v"(w4[4]), "+v"(w4[5]), "+v"(w4[6]), "+v"(w4[7]),
                          "+v"(w4[8]), "+v"(w4[9]), "+v"(w4[10]), "+v"(w4[11]),
                          "+v"(w4[12]), "+v"(w4[13]), "+v"(w4[14]), "+v"(w4[15]));
        const float bias = b_hh[row];
        const float hw   = (wid == 0) ? head_w[j] : 0.f;
        const int o1 = (wid == 0) ? 1 : 0;
        const int o2 = (wid == 2) ? 1 : 2;
        float h = hidden_init[b * H_ + j];
        unsigned sg = 0;

        for (int k = 0; k < NTILES; ++k) {
            const int s = k & 1;
            const unsigned tgt = 4u * (unsigned)((k >> 1) + 1);   // 4 producers
            while (__hip_atomic_load(&prod_done[s], __ATOMIC_ACQUIRE,
                                     __HIP_MEMORY_SCOPE_WORKGROUP) < tgt)
                __builtin_amdgcn_s_sleep(1);
            const float* xr_p = &xg_s[s][(size_t)j * XGS];
            const float* xz_p = &xg_s[s][(size_t)(H_ + j) * XGS];
            const float* xn_p = &xg_s[s][(size_t)(2 * H_ + j) * XGS];

#pragma unroll 2
            for (int t = 0; t < TILE_T; ++t, ++sg) {
                const int par = (int)(sg & 1u);
                // x reads hide under the dot (consumed after the hop)
                float xr = xr_p[t], xz = xz_p[t], xn = xn_p[t];

                // in-register h broadcast: readlane -> SGPR, fmac v,s,v
                const int hb = __builtin_bit_cast(int, h);
                float a0 = 0.f, a1 = 0.f, a2 = 0.f, a3 = 0.f;
#pragma unroll
                for (int q = 0; q < 16; ++q) {
                    float h0 = __builtin_bit_cast(float, __builtin_amdgcn_readlane(hb, 4 * q + 0));
                    float h1 = __builtin_bit_cast(float, __builtin_amdgcn_readlane(hb, 4 * q + 1));
                    float h2 = __builtin_bit_cast(float, __builtin_amdgcn_readlane(hb, 4 * q + 2));
                    float h3 = __builtin_bit_cast(float, __builtin_amdgcn_readlane(hb, 4 * q + 3));
                    a0 = fmaf(w4[q].x, h0, a0); a1 = fmaf(w4[q].y, h1, a1);
                    a2 = fmaf(w4[q].z, h2, a2); a3 = fmaf(w4[q].w, h3, a3);
                }
                float a = ((a0 + a1) + (a2 + a3)) + bias;
                const unsigned want = sg + 1;

                // publish my dot, then poll the other two (single hop)
                u64 pk = ((u64)want << 32) | (u64)__builtin_bit_cast(unsigned, a);
                __hip_atomic_store(&slot[wid][par][j], pk, __ATOMIC_RELAXED,
                                   __HIP_MEMORY_SCOPE_WORKGROUP);
                u64 v1, v2;
                do {
                    v1 = __hip_atomic_load(&slot[o1][par][j], __ATOMIC_RELAXED,
                                           __HIP_MEMORY_SCOPE_WORKGROUP);
                    v2 = __hip_atomic_load(&slot[o2][par][j], __ATOMIC_RELAXED,
                                           __HIP_MEMORY_SCOPE_WORKGROUP);
                } while ((unsigned)(v1 >> 32) != want || (unsigned)(v2 >> 32) != want);
                float b1 = __builtin_bit_cast(float, (unsigned)v1);
                float b2 = __builtin_bit_cast(float, (unsigned)v2);

                float ar, az, an;
                if (wid == 0)      { ar = a;  az = b1; an = b2; }
                else if (wid == 1) { ar = b1; az = a;  an = b2; }
                else               { ar = b1; az = b2; an = a;  }

                // replicated pointwise (identical FP ops in all 3 waves)
                float r   = __builtin_amdgcn_rcpf(1.f + __expf(-(xr + ar)));
                float z   = __builtin_amdgcn_rcpf(1.f + __expf(-(xz + az)));
                float pre = xn + r * an;
                float n   = fmaf(-2.f, __builtin_amdgcn_rcpf(__expf(2.f * pre) + 1.f), 1.f);
                h = fmaf(z, h - n, n);           // (1-z)n + zh
            }
            if (lane == 0)   // each scan wave releases the tile (producers wait 3)
                __hip_atomic_fetch_add(&cons_done[s], 1u, __ATOMIC_RELEASE,
                                       __HIP_MEMORY_SCOPE_WORKGROUP);
        }

        if (wid == 0) {   // all waves hold identical final h
            out[B_ + b * H_ + j] = h;
            float v = h * hw;
#pragma unroll
            for (int off = 32; off > 0; off >>= 1) v += __shfl_down(v, off);
            if (lane == 0) out[b] = v + head_b[0];
        }
    } else {
        // ============ producers: register-tiled GEMM (r8 verbatim) ============
        const int p  = tid - 192;        // 0..255
        const int tx = p & 7;            // t-sub: t = tx*8 + jj
        const int gy = p >> 3;           // g-sub: g = gy*6 + i
        const float* latb = lat + (size_t)b * (D_ * T_);
        unsigned phase = 0;

        auto psync = [&]() {
            if ((p & 63) == 0)
                __hip_atomic_fetch_add(&pbar, 1u, __ATOMIC_RELEASE,
                                       __HIP_MEMORY_SCOPE_WORKGROUP);
            ++phase;
            while (__hip_atomic_load(&pbar, __ATOMIC_ACQUIRE,
                                     __HIP_MEMORY_SCOPE_WORKGROUP) < 4u * phase) {}
        };

        float bias[6];
#pragma unroll
        for (int i = 0; i < 6; ++i) bias[i] = b_ih[gy * 6 + i];

        for (int k = 0; k < NTILES; ++k) {
            const int s = k & 1, m = k >> 1;
            if (m >= 1) {
                while (__hip_atomic_load(&cons_done[s], __ATOMIC_ACQUIRE,
                                         __HIP_MEMORY_SCOPE_WORKGROUP) < 3u * (unsigned)m)
                    __builtin_amdgcn_s_sleep(1);
            }
            psync();   // all producers past previous tile's lat_s/w_s

            // stage lat tile [d][t] (coalesced)
#pragma unroll
            for (int i = 0; i < 32; ++i) {
                int f = p + 256 * i;           // f = d*64 + t
                int d = f >> 6, t = f & 63;
                lat_s[f] = latb[(size_t)d * T_ + k * TILE_T + t];
            }

            float acc[8][6];
#pragma unroll
            for (int jj = 0; jj < 8; ++jj)
#pragma unroll
                for (int i = 0; i < 6; ++i) acc[jj][i] = 0.f;

            for (int kc = 0; kc < D_; kc += KC) {
                psync();   // lat_s staged / previous w_s consumed
#pragma unroll
                for (int i = 0; i < (G_ * KC) / 256; ++i) {   // 24/thread
                    int f = p + 256 * i;
                    int g = f >> 5, kk = f & 31;
                    w_s[kk * WS + g] = W_ih[(size_t)g * D_ + kc + kk];
                }
                psync();   // w_s ready
#pragma unroll 4
                for (int kk = 0; kk < KC; ++kk) {
                    f32x4 l0 = *(const f32x4*)&lat_s[(kc + kk) * 64 + tx * 8];
                    f32x4 l1 = *(const f32x4*)&lat_s[(kc + kk) * 64 + tx * 8 + 4];
                    float2 w0 = *(const float2*)&w_s[kk * WS + gy * 6];
                    float2 w1 = *(const float2*)&w_s[kk * WS + gy * 6 + 2];
                    float2 w2 = *(const float2*)&w_s[kk * WS + gy * 6 + 4];
                    float lv[8] = {l0.x, l0.y, l0.z, l0.w, l1.x, l1.y, l1.z, l1.w};
                    float wv[6] = {w0.x, w0.y, w1.x, w1.y, w2.x, w2.y};
#pragma unroll
                    for (int jj = 0; jj < 8; ++jj)
#pragma unroll
                        for (int i = 0; i < 6; ++i)
                            acc[jj][i] = fmaf(lv[jj], wv[i], acc[jj][i]);
                }
            }

            // write tile to ring slot
            float* xs = xg_s[s];
#pragma unroll
            for (int i = 0; i < 6; ++i)
#pragma unroll
                for (int jj = 0; jj < 8; ++jj)
                    xs[(size_t)(gy * 6 + i) * XGS + tx * 8 + jj] = acc[jj][i] + bias[i];

            if ((p & 63) == 0)
                __hip_atomic_fetch_add(&prod_done[s], 1u, __ATOMIC_RELEASE,
                                       __HIP_MEMORY_SCOPE_WORKGROUP);
        }
    }
}

extern "C" void kernel_launch(void* const* d_in, const int* in_sizes, int n_in,
                              void* d_out, int out_size, void* d_ws, size_t ws_size,
                              hipStream_t stream)
{
    const float* lat   = (const float*)d_in[0];
    const float* hid0  = (const float*)d_in[1];
    const float* W_ih  = (const float*)d_in[2];
    const float* W_hh  = (const float*)d_in[3];
    const float* b_ih  = (const float*)d_in[4];
    const float* b_hh  = (const float*)d_in[5];
    const float* headw = (const float*)d_in[6];
    const float* headb = (const float*)d_in[7];
    float* out = (float*)d_out;

    gru_fused<<<dim3(B_), dim3(448), 0, stream>>>(
        lat, hid0, W_ih, W_hh, b_ih, b_hh, headw, headb, out);
}

// Round 11
// 452.883 us; speedup vs baseline: 1.8907x; 1.0209x over previous
//
#include <hip/hip_runtime.h>

#define B_ 256
#define D_ 128
#define T_ 1024
#define H_ 64
#define G_ 192
#define TILE_T 64
#define NTILES (T_ / TILE_T)   // 16
#define XGS 65                 // ring t-stride: 65%32=1 -> 2-way max (free)
#define KC 32                  // producer k-chunk
#define WS 194                 // w_s g-stride

typedef float f32x4 __attribute__((ext_vector_type(4)));

// Fused GRU, 1 launch. Block = 1 batch row, 5 waves (320 thr), 1 block/CU.
//   wave 0    : scan, ALL THREE gate dots in one wave -> zero inter-wave
//               hops. Needs 192 weight VGPRs: amdgpu_waves_per_eu(2,2)
//               sets the allocator budget to 512/2 = 256 (rounds 3-5 failed
//               because waves_per_eu(1,1) was infeasible for a multi-wave
//               block and was silently ignored -> 128 target -> spill).
//   waves 1..4: register-tiled GEMM producers -> LDS ring (r8 verbatim).
// Sync via LDS atomic flags only; s_barrier once at start.
__global__ __attribute__((amdgpu_waves_per_eu(2, 2))) __launch_bounds__(320)
void gru_fused(
    const float* __restrict__ lat, const float* __restrict__ hidden_init,
    const float* __restrict__ W_ih, const float* __restrict__ W_hh,
    const float* __restrict__ b_ih, const float* __restrict__ b_hh,
    const float* __restrict__ head_w, const float* __restrict__ head_b,
    float* __restrict__ out)
{
    __shared__ float xg_s[2][G_ * XGS];     // 99,840 B ring [slot][g*XGS+t]
    __shared__ float lat_s[D_ * TILE_T];    // 32,768 B [d][t]
    __shared__ float w_s[KC * WS];          // 24,832 B [kk][g]
    __shared__ float h_s[H_];
    __shared__ unsigned prod_done[2], cons_done[2], pbar;

    const int b    = blockIdx.x;
    const int tid  = threadIdx.x;
    const int lane = tid & 63;
    const int wid  = tid >> 6;

    if (tid < 2) { prod_done[tid] = 0u; cons_done[tid] = 0u; }
    if (tid == 2) pbar = 0u;
    __syncthreads();   // only workgroup barrier (all 5 waves present)

    if (wid == 0) {
        // ========== scan: single wave, all gates, no inter-wave hops ==========
        __builtin_amdgcn_s_setprio(1);
        const int j = lane;
        f32x4 wr4[16], wz4[16], wn4[16];
        {
            const f32x4* Wr = (const f32x4*)(W_hh + (size_t)j * H_);
            const f32x4* Wz = (const f32x4*)(W_hh + (size_t)(H_ + j) * H_);
            const f32x4* Wn = (const f32x4*)(W_hh + (size_t)(2 * H_ + j) * H_);
#pragma unroll
            for (int q = 0; q < 16; ++q) { wr4[q] = Wr[q]; wz4[q] = Wz[q]; wn4[q] = Wn[q]; }
        }
        // prevent rematerialization of the 48 weight quads
        asm volatile("" : "+v"(wr4[0]), "+v"(wr4[1]), "+v"(wr4[2]), "+v"(wr4[3]),
                          "+v"(wr4[4]), "+v"(wr4[5]), "+v"(wr4[6]), "+v"(wr4[7]),
                          "+v"(wr4[8]), "+v"(wr4[9]), "+v"(wr4[10]), "+v"(wr4[11]),
                          "+v"(wr4[12]), "+v"(wr4[13]), "+v"(wr4[14]), "+v"(wr4[15]));
        asm volatile("" : "+v"(wz4[0]), "+v"(wz4[1]), "+v"(wz4[2]), "+v"(wz4[3]),
                          "+v"(wz4[4]), "+v"(wz4[5]), "+v"(wz4[6]), "+v"(wz4[7]),
                          "+v"(wz4[8]), "+v"(wz4[9]), "+v"(wz4[10]), "+v"(wz4[11]),
                          "+v"(wz4[12]), "+v"(wz4[13]), "+v"(wz4[14]), "+v"(wz4[15]));
        asm volatile("" : "+v"(wn4[0]), "+v"(wn4[1]), "+v"(wn4[2]), "+v"(wn4[3]),
                          "+v"(wn4[4]), "+v"(wn4[5]), "+v"(wn4[6]), "+v"(wn4[7]),
                          "+v"(wn4[8]), "+v"(wn4[9]), "+v"(wn4[10]), "+v"(wn4[11]),
                          "+v"(wn4[12]), "+v"(wn4[13]), "+v"(wn4[14]), "+v"(wn4[15]));
        const float br = b_hh[j], bz = b_hh[H_ + j], bn = b_hh[2 * H_ + j];
        const float hw = head_w[j];
        float h = hidden_init[b * H_ + j];

        for (int k = 0; k < NTILES; ++k) {
            const int s = k & 1;
            const unsigned tgt = 4u * (unsigned)((k >> 1) + 1);   // 4 producers
            while (__hip_atomic_load(&prod_done[s], __ATOMIC_ACQUIRE,
                                     __HIP_MEMORY_SCOPE_WORKGROUP) < tgt)
                __builtin_amdgcn_s_sleep(1);
            const float* xr_p = &xg_s[s][(size_t)j * XGS];
            const float* xz_p = &xg_s[s][(size_t)(H_ + j) * XGS];
            const float* xn_p = &xg_s[s][(size_t)(2 * H_ + j) * XGS];

#pragma unroll 2
            for (int t = 0; t < TILE_T; ++t) {
                h_s[j] = h;                       // within-wave: DS in-order
                float xr = xr_p[t], xz = xz_p[t], xn = xn_p[t];
                const f32x4* h4 = (const f32x4*)h_s;
                f32x4 aR = {0.f, 0.f, 0.f, 0.f};
                f32x4 aZ = {0.f, 0.f, 0.f, 0.f};
                f32x4 aN = {0.f, 0.f, 0.f, 0.f};
#pragma unroll
                for (int q = 0; q < 16; ++q) {
                    f32x4 hv = h4[q];             // broadcast read, shared by 3 gates
                    aR += wr4[q] * hv;            // v_pk_fma_f32 (contract=fast)
                    aZ += wz4[q] * hv;
                    aN += wn4[q] * hv;
                }
                float ar = ((aR.x + aR.y) + (aR.z + aR.w)) + br;
                float az = ((aZ.x + aZ.y) + (aZ.z + aZ.w)) + bz;
                float an = ((aN.x + aN.y) + (aN.z + aN.w)) + bn;

                float r   = __builtin_amdgcn_rcpf(1.f + __expf(-(xr + ar)));
                float z   = __builtin_amdgcn_rcpf(1.f + __expf(-(xz + az)));
                float pre = xn + r * an;
                float n   = fmaf(-2.f, __builtin_amdgcn_rcpf(__expf(2.f * pre) + 1.f), 1.f);
                h = fmaf(z, h - n, n);            // (1-z)n + zh
            }
            if (lane == 0)
                __hip_atomic_fetch_add(&cons_done[s], 1u, __ATOMIC_RELEASE,
                                       __HIP_MEMORY_SCOPE_WORKGROUP);
        }

        // epilogue: final hidden + head
        out[B_ + b * H_ + j] = h;
        float v = h * hw;
#pragma unroll
        for (int off = 32; off > 0; off >>= 1) v += __shfl_down(v, off);
        if (lane == 0) out[b] = v + head_b[0];
    } else {
        // ============ producers: register-tiled GEMM (r8 verbatim) ============
        const int p  = tid - 64;         // 0..255
        const int tx = p & 7;            // t-sub: t = tx*8 + jj
        const int gy = p >> 3;           // g-sub: g = gy*6 + i
        const float* latb = lat + (size_t)b * (D_ * T_);
        unsigned phase = 0;

        auto psync = [&]() {
            if ((p & 63) == 0)
                __hip_atomic_fetch_add(&pbar, 1u, __ATOMIC_RELEASE,
                                       __HIP_MEMORY_SCOPE_WORKGROUP);
            ++phase;
            while (__hip_atomic_load(&pbar, __ATOMIC_ACQUIRE,
                                     __HIP_MEMORY_SCOPE_WORKGROUP) < 4u * phase) {}
        };

        float bias[6];
#pragma unroll
        for (int i = 0; i < 6; ++i) bias[i] = b_ih[gy * 6 + i];

        for (int k = 0; k < NTILES; ++k) {
            const int s = k & 1, m = k >> 1;
            if (m >= 1) {
                while (__hip_atomic_load(&cons_done[s], __ATOMIC_ACQUIRE,
                                         __HIP_MEMORY_SCOPE_WORKGROUP) < (unsigned)m)
                    __builtin_amdgcn_s_sleep(1);
            }
            psync();   // all producers past previous tile's lat_s/w_s

            // stage lat tile [d][t] (coalesced)
#pragma unroll
            for (int i = 0; i < 32; ++i) {
                int f = p + 256 * i;           // f = d*64 + t
                int d = f >> 6, t = f & 63;
                lat_s[f] = latb[(size_t)d * T_ + k * TILE_T + t];
            }

            float acc[8][6];
#pragma unroll
            for (int jj = 0; jj < 8; ++jj)
#pragma unroll
                for (int i = 0; i < 6; ++i) acc[jj][i] = 0.f;

            for (int kc = 0; kc < D_; kc += KC) {
                psync();   // lat_s staged / previous w_s consumed
#pragma unroll
                for (int i = 0; i < (G_ * KC) / 256; ++i) {   // 24/thread
                    int f = p + 256 * i;
                    int g = f >> 5, kk = f & 31;
                    w_s[kk * WS + g] = W_ih[(size_t)g * D_ + kc + kk];
                }
                psync();   // w_s ready
#pragma unroll 4
                for (int kk = 0; kk < KC; ++kk) {
                    f32x4 l0 = *(const f32x4*)&lat_s[(kc + kk) * 64 + tx * 8];
                    f32x4 l1 = *(const f32x4*)&lat_s[(kc + kk) * 64 + tx * 8 + 4];
                    float2 w0 = *(const float2*)&w_s[kk * WS + gy * 6];
                    float2 w1 = *(const float2*)&w_s[kk * WS + gy * 6 + 2];
                    float2 w2 = *(const float2*)&w_s[kk * WS + gy * 6 + 4];
                    float lv[8] = {l0.x, l0.y, l0.z, l0.w, l1.x, l1.y, l1.z, l1.w};
                    float wv[6] = {w0.x, w0.y, w1.x, w1.y, w2.x, w2.y};
#pragma unroll
                    for (int jj = 0; jj < 8; ++jj)
#pragma unroll
                        for (int i = 0; i < 6; ++i)
                            acc[jj][i] = fmaf(lv[jj], wv[i], acc[jj][i]);
                }
            }

            // write tile to ring slot
            float* xs = xg_s[s];
#pragma unroll
            for (int i = 0; i < 6; ++i)
#pragma unroll
                for (int jj = 0; jj < 8; ++jj)
                    xs[(size_t)(gy * 6 + i) * XGS + tx * 8 + jj] = acc[jj][i] + bias[i];

            if ((p & 63) == 0)
                __hip_atomic_fetch_add(&prod_done[s], 1u, __ATOMIC_RELEASE,
                                       __HIP_MEMORY_SCOPE_WORKGROUP);
        }
    }
}

extern "C" void kernel_launch(void* const* d_in, const int* in_sizes, int n_in,
                              void* d_out, int out_size, void* d_ws, size_t ws_size,
                              hipStream_t stream)
{
    const float* lat   = (const float*)d_in[0];
    const float* hid0  = (const float*)d_in[1];
    const float* W_ih  = (const float*)d_in[2];
    const float* W_hh  = (const float*)d_in[3];
    const float* b_ih  = (const float*)d_in[4];
    const float* b_hh  = (const float*)d_in[5];
    const float* headw = (const float*)d_in[6];
    const float* headb = (const float*)d_in[7];
    float* out = (float*)d_out;

    gru_fused<<<dim3(B_), dim3(320), 0, stream>>>(
        lat, hid0, W_ih, W_hh, b_ih, b_hh, headw, headb, out);
}